// Round 7
// baseline (506.364 us; speedup 1.0000x reference)
//
#include <hip/hip_runtime.h>
#include <hip/hip_bf16.h>

#define NN   50000
#define NE   640000
#define NPE  500000
#define FEPS 1e-5f

typedef __attribute__((ext_vector_type(8))) short          bf16x8;
typedef __attribute__((ext_vector_type(8))) unsigned short u16x8;
typedef __attribute__((ext_vector_type(4))) float          f32x4;

__device__ inline float b2f(unsigned short u) {
    union { unsigned int i; float f; } c; c.i = (unsigned int)u << 16; return c.f;
}
__device__ inline unsigned short f2b(float f) {
    __hip_bfloat16 h = __float2bfloat16(f);
    return *reinterpret_cast<unsigned short*>(&h);
}

// ---------------- fused init: zero cnt/cursor + fp32->bf16 conversions + BN2 fold ----------------
// blocks [0,98): zero 25088 int4 ; [98,3223): x ; [3223,3335): weights ; 3335: fold2
__global__ __launch_bounds__(256) void k_init(
    int4* __restrict__ zdst,
    const float* __restrict__ x, unsigned short* __restrict__ xbf,
    const float* __restrict__ W1l, const float* __restrict__ W1r,
    const float* __restrict__ W2l, const float* __restrict__ W2r,
    const float* __restrict__ pW1, const float* __restrict__ pW2,
    unsigned short* __restrict__ wdst,
    const float* __restrict__ pb2, const float* __restrict__ pg2,
    const float* __restrict__ pbb2, const float* __restrict__ pm2,
    const float* __restrict__ pv2, float2* __restrict__ fold2) {
    int b = blockIdx.x, t = threadIdx.x;
    if (b < 98) {
        int i = b * 256 + t;
        if (i < 25088) zdst[i] = make_int4(0, 0, 0, 0);
        return;
    }
    if (b == 3335) {
        if (t < 128) {
            float sc = pg2[t] * rsqrtf(pv2[t] + FEPS);
            float off = pb2[t] * sc + pbb2[t] - pm2[t] * sc;
            fold2[t] = make_float2(sc, off);
        }
        return;
    }
    const float* src;
    size_t off;
    if (b < 3223) {
        int i = (b - 98) * 256 + t;
        if (i >= 800000) return;
        const float4* p = (const float4*)x + 2 * (size_t)i;
        float4 a = p[0], c = p[1];
        u16x8 o;
        o[0]=f2b(a.x); o[1]=f2b(a.y); o[2]=f2b(a.z); o[3]=f2b(a.w);
        o[4]=f2b(c.x); o[5]=f2b(c.y); o[6]=f2b(c.z); o[7]=f2b(c.w);
        *((u16x8*)xbf + i) = o;
        return;
    }
    int i = (b - 3223) * 256 + t;   // 0..28671
    if (i >= 28672) return;
    if      (i < 4096)  { src = W1l; off = i; }
    else if (i < 8192)  { src = W1r; off = i - 4096; }
    else if (i < 12288) { src = W2l; off = i - 8192; }
    else if (i < 16384) { src = W2r; off = i - 12288; }
    else if (i < 24576) { src = pW1; off = i - 16384; }
    else                { src = pW2; off = i - 24576; }
    const float4* p = (const float4*)src + 2 * off;
    float4 a = p[0], c = p[1];
    u16x8 o;
    o[0]=f2b(a.x); o[1]=f2b(a.y); o[2]=f2b(a.z); o[3]=f2b(a.w);
    o[4]=f2b(c.x); o[5]=f2b(c.y); o[6]=f2b(c.z); o[7]=f2b(c.w);
    *((u16x8*)wdst + i) = o;
}

// ---------------- CSR build ----------------
__global__ void k_hist(const int* __restrict__ key, int* __restrict__ cnt, int n) {
    int e = blockIdx.x * blockDim.x + threadIdx.x;
    if (e < n) atomicAdd(&cnt[key[e]], 1);
}

__global__ void k_scan1(const int* __restrict__ cnt, int* __restrict__ part) {
    int t = threadIdx.x, lane = t & 63, w = t >> 6;
    int i = blockIdx.x * 256 + t;
    int v = (i < NN) ? cnt[i] : 0;
#pragma unroll
    for (int d = 1; d < 64; d <<= 1) v += __shfl_xor(v, d, 64);
    __shared__ int ws[4];
    if (lane == 0) ws[w] = v;
    __syncthreads();
    if (t == 0) part[blockIdx.x] = ws[0] + ws[1] + ws[2] + ws[3];
}

__global__ void k_scan2(int* __restrict__ part) {   // in-place -> exclusive bases
    int t = threadIdx.x, lane = t & 63, w = t >> 6;
    int v = (t < 196) ? part[t] : 0;
    int s = v;
#pragma unroll
    for (int d = 1; d < 64; d <<= 1) { int u = __shfl_up(s, d, 64); if (lane >= d) s += u; }
    __shared__ int ws[4];
    if (lane == 63) ws[w] = s;
    __syncthreads();
    if (t == 0) { int a = 0; for (int k = 0; k < 4; ++k) { int tmp = ws[k]; ws[k] = a; a += tmp; } }
    __syncthreads();
    if (t < 196) part[t] = ws[w] + s - v;
}

__global__ void k_scan3(const int* __restrict__ cnt, const int* __restrict__ part,
                        int* __restrict__ rowptr) {
    int t = threadIdx.x, lane = t & 63, w = t >> 6;
    int i = blockIdx.x * 256 + t;
    int v = (i < NN) ? cnt[i] : 0;
    int s = v;
#pragma unroll
    for (int d = 1; d < 64; d <<= 1) { int u = __shfl_up(s, d, 64); if (lane >= d) s += u; }
    __shared__ int ws[4];
    if (lane == 63) ws[w] = s;
    __syncthreads();
    if (t == 0) { int a = 0; for (int k = 0; k < 4; ++k) { int tmp = ws[k]; ws[k] = a; a += tmp; } }
    __syncthreads();
    if (i <= NN) rowptr[i] = part[blockIdx.x] + ws[w] + s - v;
}

__global__ void k_fill(const int* __restrict__ src, const int* __restrict__ dst,
                       const int* __restrict__ rowptr, int* __restrict__ cursor,
                       int* __restrict__ col) {
    int e = blockIdx.x * blockDim.x + threadIdx.x;
    if (e >= NE) return;
    int d = dst[e];
    int slot = atomicAdd(&cursor[d], 1);
    col[rowptr[d] + slot] = src[e];
}

// ---------------- gather-mean (CSR), 128-ch rows, 8-deep pipelined ----------------
__global__ __launch_bounds__(256) void k_mean(const unsigned short* __restrict__ feat,
                                              const int* __restrict__ rowptr,
                                              const int* __restrict__ col,
                                              unsigned short* __restrict__ outm) {
    int node = blockIdx.x * 4 + (threadIdx.x >> 6);
    int lane = threadIdx.x & 63;
    if (node >= NN) return;
    int beg = rowptr[node], end = rowptr[node + 1];
    float a0 = 0.f, a1 = 0.f;
    int j = beg;
    for (; j + 8 <= end; j += 8) {
        int s[8];
#pragma unroll
        for (int k = 0; k < 8; ++k) s[k] = col[j + k];
        unsigned int v[8];
#pragma unroll
        for (int k = 0; k < 8; ++k)
            v[k] = *(const unsigned int*)(feat + (size_t)s[k] * 128 + lane * 2);
#pragma unroll
        for (int k = 0; k < 8; ++k) { a0 += b2f(v[k] & 0xffff); a1 += b2f(v[k] >> 16); }
    }
    if (j + 4 <= end) {
        int s[4];
#pragma unroll
        for (int k = 0; k < 4; ++k) s[k] = col[j + k];
        unsigned int v[4];
#pragma unroll
        for (int k = 0; k < 4; ++k)
            v[k] = *(const unsigned int*)(feat + (size_t)s[k] * 128 + lane * 2);
#pragma unroll
        for (int k = 0; k < 4; ++k) { a0 += b2f(v[k] & 0xffff); a1 += b2f(v[k] >> 16); }
        j += 4;
    }
    for (; j < end; ++j) {
        int s = col[j];
        unsigned int v = *(const unsigned int*)(feat + (size_t)s * 128 + lane * 2);
        a0 += b2f(v & 0xffff); a1 += b2f(v >> 16);
    }
    float inv = 1.f / fmaxf((float)(end - beg), 1.f);
    unsigned int v = (unsigned int)f2b(a0 * inv) | ((unsigned int)f2b(a1 * inv) << 16);
    *(unsigned int*)(outm + (size_t)node * 128 + lane * 2) = v;
}

// ---------------- fused SAGE1 + layer-2 linears ----------------
__global__ __launch_bounds__(256) void k_sage12(
    const unsigned short* __restrict__ mean, const unsigned short* __restrict__ self,
    const unsigned short* __restrict__ Wl, const unsigned short* __restrict__ Wr,   // [256][128]
    const float* __restrict__ b, const float* __restrict__ bg, const float* __restrict__ bb,
    const float* __restrict__ bm, const float* __restrict__ bv,
    const unsigned short* __restrict__ W2l, const unsigned short* __restrict__ W2r, // [128][256]
    const float* __restrict__ b2,
    unsigned short* __restrict__ Y, unsigned short* __restrict__ S) {
    __shared__ unsigned short AB[64 * 256];           // 32 KB: ms|xs, then reused as hs
    unsigned short* ms = AB;
    unsigned short* xs = AB + 64 * 128;
    int t = threadIdx.x;
    int n0 = blockIdx.x * 64;
    for (int j = 0; j < 4; ++j) {
        int idx = t + j * 256;
        int row = idx >> 4, c16 = idx & 15;
        int node = n0 + row;
        u16x8 v = {0,0,0,0,0,0,0,0}, v2 = {0,0,0,0,0,0,0,0};
        if (node < NN) {
            v  = *(const u16x8*)(mean + (size_t)node * 128 + c16 * 8);
            v2 = *(const u16x8*)(self + (size_t)node * 128 + c16 * 8);
        }
        int byte = row * 256 + ((c16 * 16) ^ ((row & 7) << 4));
        *(u16x8*)((char*)ms + byte) = v;
        *(u16x8*)((char*)xs + byte) = v2;
    }
    __syncthreads();
    int w = t >> 6, l = t & 63, lr = l & 15, lh = l >> 4;
    f32x4 acc[4][4];
#pragma unroll
    for (int mi = 0; mi < 4; ++mi)
#pragma unroll
        for (int ni = 0; ni < 4; ++ni) { acc[mi][ni][0]=0; acc[mi][ni][1]=0; acc[mi][ni][2]=0; acc[mi][ni][3]=0; }
#pragma unroll
    for (int half = 0; half < 2; ++half) {
        const unsigned short* A = half ? xs : ms;
        const unsigned short* W = half ? Wr : Wl;
#pragma unroll
        for (int ks = 0; ks < 4; ++ks) {
            int k0 = ks * 32;
            bf16x8 a[4], wf[4];
#pragma unroll
            for (int mi = 0; mi < 4; ++mi) {
                int row = mi * 16 + lr;
                int byte = row * 256 + ((k0 * 2 + lh * 16) ^ ((row & 7) << 4));
                a[mi] = *(const bf16x8*)((const char*)A + byte);
            }
#pragma unroll
            for (int ni = 0; ni < 4; ++ni) {
                int wrow = w * 64 + ni * 16 + lr;
                wf[ni] = *(const bf16x8*)(W + (size_t)wrow * 128 + k0 + lh * 8);
            }
#pragma unroll
            for (int mi = 0; mi < 4; ++mi)
#pragma unroll
                for (int ni = 0; ni < 4; ++ni)
                    acc[mi][ni] = __builtin_amdgcn_mfma_f32_16x16x32_bf16(a[mi], wf[ni], acc[mi][ni], 0, 0, 0);
        }
    }
    __syncthreads();   // ms/xs reads done; reuse AB as hs [64][256] (512B rows, swizzled)
#pragma unroll
    for (int ni = 0; ni < 4; ++ni) {
        int ch = w * 64 + ni * 16 + lr;
        float sc = bg[ch] * rsqrtf(bv[ch] + FEPS);
        float sh = bb[ch] - bm[ch] * sc;
        float bias = b[ch];
#pragma unroll
        for (int mi = 0; mi < 4; ++mi)
#pragma unroll
            for (int r = 0; r < 4; ++r) {
                int row = mi * 16 + lh * 4 + r;
                float vv = fmaxf((acc[mi][ni][r] + bias) * sc + sh, 0.f);
                int byte = row * 512 + ((ch * 2) ^ ((row & 7) << 4));
                *(unsigned short*)((char*)AB + byte) = f2b(vv);
            }
    }
    __syncthreads();
    f32x4 aY[4][2], aS[4][2];
#pragma unroll
    for (int mi = 0; mi < 4; ++mi)
#pragma unroll
        for (int ni = 0; ni < 2; ++ni) {
            aY[mi][ni][0]=0; aY[mi][ni][1]=0; aY[mi][ni][2]=0; aY[mi][ni][3]=0;
            aS[mi][ni][0]=0; aS[mi][ni][1]=0; aS[mi][ni][2]=0; aS[mi][ni][3]=0;
        }
#pragma unroll
    for (int ks = 0; ks < 8; ++ks) {
        int k0 = ks * 32;
        bf16x8 a[4], wl[2], wr[2];
#pragma unroll
        for (int mi = 0; mi < 4; ++mi) {
            int row = mi * 16 + lr;
            int byte = row * 512 + ((k0 * 2 + lh * 16) ^ ((row & 7) << 4));
            a[mi] = *(const bf16x8*)((const char*)AB + byte);
        }
#pragma unroll
        for (int ni = 0; ni < 2; ++ni) {
            int wrow = w * 32 + ni * 16 + lr;
            wl[ni] = *(const bf16x8*)(W2l + (size_t)wrow * 256 + k0 + lh * 8);
            wr[ni] = *(const bf16x8*)(W2r + (size_t)wrow * 256 + k0 + lh * 8);
        }
#pragma unroll
        for (int mi = 0; mi < 4; ++mi)
#pragma unroll
            for (int ni = 0; ni < 2; ++ni) {
                aY[mi][ni] = __builtin_amdgcn_mfma_f32_16x16x32_bf16(a[mi], wl[ni], aY[mi][ni], 0, 0, 0);
                aS[mi][ni] = __builtin_amdgcn_mfma_f32_16x16x32_bf16(a[mi], wr[ni], aS[mi][ni], 0, 0, 0);
            }
    }
#pragma unroll
    for (int ni = 0; ni < 2; ++ni) {
        int ch = w * 32 + ni * 16 + lr;
        float bias = b2[ch];
#pragma unroll
        for (int mi = 0; mi < 4; ++mi)
#pragma unroll
            for (int r = 0; r < 4; ++r) {
                int node = n0 + mi * 16 + lh * 4 + r;
                if (node < NN) {
                    Y[(size_t)node * 128 + ch] = f2b(aY[mi][ni][r]);
                    S[(size_t)node * 128 + ch] = f2b(aS[mi][ni][r] + bias);
                }
            }
    }
}

// ---------------- decoder precompute: z=S+mY; Pa=(z@W1a^T)*sc1+c1 ; Pb=(z@W1b^T)*sc1 ----------------
__global__ __launch_bounds__(256) void k_prep(
    const unsigned short* __restrict__ S,      // [NN][128]
    const unsigned short* __restrict__ mY,     // [NN][128]
    const unsigned short* __restrict__ W1,     // [256][256] bf16
    const float* __restrict__ b1, const float* __restrict__ g1,
    const float* __restrict__ be1, const float* __restrict__ m1, const float* __restrict__ v1,
    unsigned short* __restrict__ Pa, unsigned short* __restrict__ Pb) {
    __shared__ unsigned short zs[64 * 128];
    int t = threadIdx.x;
    int tile = blockIdx.x >> 1, side = blockIdx.x & 1;
    int n0 = tile * 64;
    for (int j = 0; j < 4; ++j) {
        int idx = t + j * 256;
        int row = idx >> 4, c16 = idx & 15;
        int node = n0 + row;
        u16x8 o = {0,0,0,0,0,0,0,0};
        if (node < NN) {
            u16x8 sv = *(const u16x8*)(S  + (size_t)node * 128 + c16 * 8);
            u16x8 mv = *(const u16x8*)(mY + (size_t)node * 128 + c16 * 8);
#pragma unroll
            for (int jj = 0; jj < 8; ++jj)
                o[jj] = f2b(b2f((unsigned short)sv[jj]) + b2f((unsigned short)mv[jj]));
        }
        int byte = row * 256 + ((c16 * 16) ^ ((row & 7) << 4));
        *(u16x8*)((char*)zs + byte) = o;
    }
    __syncthreads();
    int w = t >> 6, l = t & 63, lr = l & 15, lh = l >> 4;
    f32x4 acc[4][4];
#pragma unroll
    for (int mi = 0; mi < 4; ++mi)
#pragma unroll
        for (int ni = 0; ni < 4; ++ni) { acc[mi][ni][0]=0; acc[mi][ni][1]=0; acc[mi][ni][2]=0; acc[mi][ni][3]=0; }
#pragma unroll
    for (int ks = 0; ks < 4; ++ks) {
        int k0 = ks * 32;
        bf16x8 a[4], wf[4];
#pragma unroll
        for (int mi = 0; mi < 4; ++mi) {
            int row = mi * 16 + lr;
            int byte = row * 256 + ((k0 * 2 + lh * 16) ^ ((row & 7) << 4));
            a[mi] = *(const bf16x8*)((const char*)zs + byte);
        }
#pragma unroll
        for (int ni = 0; ni < 4; ++ni) {
            int ch = w * 64 + ni * 16 + lr;
            wf[ni] = *(const bf16x8*)(W1 + (size_t)ch * 256 + side * 128 + k0 + lh * 8);
        }
#pragma unroll
        for (int mi = 0; mi < 4; ++mi)
#pragma unroll
            for (int ni = 0; ni < 4; ++ni)
                acc[mi][ni] = __builtin_amdgcn_mfma_f32_16x16x32_bf16(a[mi], wf[ni], acc[mi][ni], 0, 0, 0);
    }
    unsigned short* P = side ? Pb : Pa;
#pragma unroll
    for (int ni = 0; ni < 4; ++ni) {
        int ch = w * 64 + ni * 16 + lr;
        float sc = g1[ch] * rsqrtf(v1[ch] + FEPS);
        float add = side ? 0.f : ((b1[ch] - m1[ch]) * sc + be1[ch]);
#pragma unroll
        for (int mi = 0; mi < 4; ++mi)
#pragma unroll
            for (int r = 0; r < 4; ++r) {
                int node = n0 + mi * 16 + lh * 4 + r;
                if (node < NN)
                    P[(size_t)node * 256 + ch] = f2b(acc[mi][ni][r] * sc + add);
            }
    }
}

// ---------------- fused decoder, barrier-free / LDS-free: each wave owns 16 edges ----------------
// Gathers land directly in MFMA A-fragment layout (lane lr = edge, lh = k-slot).
// Bit-identical math to the LDS-staged version.
__global__ __launch_bounds__(256, 5) void k_mlp(
    const unsigned short* __restrict__ Pa, const unsigned short* __restrict__ Pb,
    const int* __restrict__ pu, const int* __restrict__ pv,
    const unsigned short* __restrict__ W2,       // [128][256] bf16
    const float2* __restrict__ fold2,            // per-ch (scale, offset) of BN2 (+bias)
    const float* __restrict__ W3, const float* __restrict__ b3,
    float* __restrict__ out) {
    int t = threadIdx.x;
    int w = t >> 6, l = t & 63, lr = l & 15, lh = l >> 4;
    int we0 = blockIdx.x * 64 + w * 16;          // this wave's 16 edges
    int eidx = we0 + lr;
    int u = 0, v = 0;
    if (eidx < NPE) { u = pu[eidx]; v = pv[eidx]; }
    const u16x8* rowA = (const u16x8*)(Pa + (size_t)u * 256 + lh * 8);
    const u16x8* rowB = (const u16x8*)(Pb + (size_t)v * 256 + lh * 8);
    // rowX[ks*4] = 16B at k-offset ks*32 + lh*8 elements
    f32x4 acc[8];
#pragma unroll
    for (int ni = 0; ni < 8; ++ni) { acc[ni][0]=0; acc[ni][1]=0; acc[ni][2]=0; acc[ni][3]=0; }
    u16x8 pa0 = rowA[0], pb0 = rowB[0];
    u16x8 pa1 = rowA[4], pb1 = rowB[4];
#pragma unroll
    for (int ks = 0; ks < 8; ++ks) {
        bf16x8 af;
#pragma unroll
        for (int jj = 0; jj < 8; ++jj) {
            float f = fmaxf(b2f((unsigned short)pa0[jj]) + b2f((unsigned short)pb0[jj]), 0.f);
            af[jj] = (short)f2b(f);
        }
        pa0 = pa1; pb0 = pb1;
        if (ks < 6) { pa1 = rowA[(ks + 2) * 4]; pb1 = rowB[(ks + 2) * 4]; }
#pragma unroll
        for (int ni = 0; ni < 8; ++ni) {
            bf16x8 wf = *(const bf16x8*)(W2 + (size_t)(ni * 16 + lr) * 256 + ks * 32 + lh * 8);
            acc[ni] = __builtin_amdgcn_mfma_f32_16x16x32_bf16(af, wf, acc[ni], 0, 0, 0);
        }
    }
    // epilogue: q2 = relu(acc*sc + off); partial dot with W3; reduce over 16 lr-lanes
    float p0 = 0.f, p1 = 0.f, p2 = 0.f, p3 = 0.f;
#pragma unroll
    for (int ni = 0; ni < 8; ++ni) {
        int ch = ni * 16 + lr;
        float2 f = fold2[ch];
        float w3 = W3[ch];
        p0 += fmaxf(acc[ni][0] * f.x + f.y, 0.f) * w3;
        p1 += fmaxf(acc[ni][1] * f.x + f.y, 0.f) * w3;
        p2 += fmaxf(acc[ni][2] * f.x + f.y, 0.f) * w3;
        p3 += fmaxf(acc[ni][3] * f.x + f.y, 0.f) * w3;
    }
#pragma unroll
    for (int d = 1; d < 16; d <<= 1) {
        p0 += __shfl_xor(p0, d, 16);
        p1 += __shfl_xor(p1, d, 16);
        p2 += __shfl_xor(p2, d, 16);
        p3 += __shfl_xor(p3, d, 16);
    }
    if (lr < 4) {
        int oe = we0 + lh * 4 + lr;               // D-row = lh*4 + r ; lane lr writes r = lr
        float pr = (lr == 0) ? p0 : (lr == 1) ? p1 : (lr == 2) ? p2 : p3;
        if (oe < NPE) out[oe] = pr + b3[0];
    }
}

extern "C" void kernel_launch(void* const* d_in, const int* in_sizes, int n_in,
                              void* d_out, int out_size, void* d_ws, size_t ws_size,
                              hipStream_t stream) {
    const float* x    = (const float*)d_in[0];
    const int*   ei   = (const int*)d_in[1];
    const int*   pei  = (const int*)d_in[2];
    const float* W1l  = (const float*)d_in[3];
    const float* W1r  = (const float*)d_in[4];
    const float* b1   = (const float*)d_in[5];
    const float* bn1g = (const float*)d_in[6];
    const float* bn1b = (const float*)d_in[7];
    const float* bn1m = (const float*)d_in[8];
    const float* bn1v = (const float*)d_in[9];
    const float* W2l  = (const float*)d_in[10];
    const float* W2r  = (const float*)d_in[11];
    const float* b2   = (const float*)d_in[12];
    const float* pW1  = (const float*)d_in[13];
    const float* pb1  = (const float*)d_in[14];
    const float* pg1  = (const float*)d_in[15];
    const float* pbb1 = (const float*)d_in[16];
    const float* pm1  = (const float*)d_in[17];
    const float* pv1  = (const float*)d_in[18];
    const float* pW2  = (const float*)d_in[19];
    const float* pb2  = (const float*)d_in[20];
    const float* pg2  = (const float*)d_in[21];
    const float* pbb2 = (const float*)d_in[22];
    const float* pm2  = (const float*)d_in[23];
    const float* pv2  = (const float*)d_in[24];
    const float* pW3  = (const float*)d_in[25];
    const float* pb3  = (const float*)d_in[26];
    float* out = (float*)d_out;

    const int* src = ei;
    const int* dst = ei + NE;
    const int* pu  = pei;
    const int* pv  = pei + NPE;

    char* p = (char*)d_ws;
    auto alloc = [&](size_t bytes) -> char* {
        char* r = p; p += (bytes + 255) & ~(size_t)255; return r;
    };
    int* cnt     = (int*)alloc((size_t)NN * 4);          // zeroed by k_init (with cursor)
    int* cursor  = (int*)alloc((size_t)NN * 4);
    int* part    = (int*)alloc(256 * 4);
    int* rowptr  = (int*)alloc((size_t)(NN + 1) * 4);
    int* col     = (int*)alloc((size_t)NE * 4);
    unsigned short* xbf  = (unsigned short*)alloc((size_t)NN * 128 * 2);  // -> Pb lower half
    unsigned short* mx   = (unsigned short*)alloc((size_t)NN * 128 * 2);  // -> Pb upper half
    unsigned short* Ybf  = (unsigned short*)alloc((size_t)NN * 128 * 2);
    unsigned short* mY   = (unsigned short*)alloc((size_t)NN * 128 * 2);
    unsigned short* Sbf  = (unsigned short*)alloc((size_t)NN * 128 * 2);
    unsigned short* Pa   = (unsigned short*)alloc((size_t)NN * 256 * 2);
    unsigned short* W1lb = (unsigned short*)alloc((size_t)256 * 128 * 2); // contiguous weight block
    unsigned short* W1rb = (unsigned short*)alloc((size_t)256 * 128 * 2);
    unsigned short* W2lb = (unsigned short*)alloc((size_t)128 * 256 * 2);
    unsigned short* W2rb = (unsigned short*)alloc((size_t)128 * 256 * 2);
    unsigned short* pW1b = (unsigned short*)alloc((size_t)256 * 256 * 2);
    unsigned short* pW2b = (unsigned short*)alloc((size_t)128 * 256 * 2);
    float2* fold2        = (float2*)alloc(128 * 8);
    unsigned short* Pb = xbf;   // [NN][256] spanning xbf+mx (dead after k_sage12/k_mean)

    // 1. fused zero (cnt,cursor) + bf16 conversions + BN2 fold
    k_init<<<3336, 256, 0, stream>>>((int4*)cnt, x, xbf,
                                     W1l, W1r, W2l, W2r, pW1, pW2, W1lb,
                                     pb2, pg2, pbb2, pm2, pv2, fold2);
    // CSR build (aggregation, keyed by dst)
    k_hist<<<2500, 256, 0, stream>>>(dst, cnt, NE);
    k_scan1<<<196, 256, 0, stream>>>(cnt, part);
    k_scan2<<<1, 256, 0, stream>>>(part);
    k_scan3<<<196, 256, 0, stream>>>(cnt, part, rowptr);
    k_fill<<<2500, 256, 0, stream>>>(src, dst, rowptr, cursor, col);

    // encoder
    k_mean<<<12500, 256, 0, stream>>>(xbf, rowptr, col, mx);
    k_sage12<<<782, 256, 0, stream>>>(mx, xbf, W1lb, W1rb, b1, bn1g, bn1b, bn1m, bn1v,
                                      W2lb, W2rb, b2, Ybf, Sbf);
    k_mean<<<12500, 256, 0, stream>>>(Ybf, rowptr, col, mY);

    // decoder precompute (Pb overwrites xbf+mx — dead now)
    k_prep<<<1564, 256, 0, stream>>>(Sbf, mY, pW1b, pb1, pg1, pbb1, pm1, pv1, Pa, Pb);

    // fused decoder: one wave per 16 edges, no LDS, no barriers
    k_mlp<<<(NPE + 63) / 64, 256, 0, stream>>>(Pa, Pb, pu, pv,
                                               pW2b, fold2, pW3, pb3, out);
}

// Round 8
// 437.002 us; speedup vs baseline: 1.1587x; 1.1587x over previous
//
#include <hip/hip_runtime.h>
#include <hip/hip_bf16.h>

#define NN   50000
#define NE   640000
#define NPE  500000
#define FEPS 1e-5f

typedef __attribute__((ext_vector_type(8))) short          bf16x8;
typedef __attribute__((ext_vector_type(8))) unsigned short u16x8;
typedef __attribute__((ext_vector_type(4))) float          f32x4;

__device__ inline float b2f(unsigned short u) {
    union { unsigned int i; float f; } c; c.i = (unsigned int)u << 16; return c.f;
}
__device__ inline unsigned short f2b(float f) {
    __hip_bfloat16 h = __float2bfloat16(f);
    return *reinterpret_cast<unsigned short*>(&h);
}

// ---------------- fused init: zero cnt/cursor + all fp32->bf16 conversions ----------------
// blocks [0,98): zero 25088 int4 ; [98,3223): x ; [3223,3335): weights (contiguous dst)
__global__ __launch_bounds__(256) void k_init(
    int4* __restrict__ zdst,
    const float* __restrict__ x, unsigned short* __restrict__ xbf,
    const float* __restrict__ W1l, const float* __restrict__ W1r,
    const float* __restrict__ W2l, const float* __restrict__ W2r,
    const float* __restrict__ pW1, const float* __restrict__ pW2,
    unsigned short* __restrict__ wdst) {
    int b = blockIdx.x, t = threadIdx.x;
    if (b < 98) {
        int i = b * 256 + t;
        if (i < 25088) zdst[i] = make_int4(0, 0, 0, 0);
        return;
    }
    const float* src;
    size_t off;
    if (b < 3223) {
        int i = (b - 98) * 256 + t;
        if (i >= 800000) return;
        const float4* p = (const float4*)x + 2 * (size_t)i;
        float4 a = p[0], c = p[1];
        u16x8 o;
        o[0]=f2b(a.x); o[1]=f2b(a.y); o[2]=f2b(a.z); o[3]=f2b(a.w);
        o[4]=f2b(c.x); o[5]=f2b(c.y); o[6]=f2b(c.z); o[7]=f2b(c.w);
        *((u16x8*)xbf + i) = o;
        return;
    }
    int i = (b - 3223) * 256 + t;   // 0..28671
    if (i >= 28672) return;
    if      (i < 4096)  { src = W1l; off = i; }
    else if (i < 8192)  { src = W1r; off = i - 4096; }
    else if (i < 12288) { src = W2l; off = i - 8192; }
    else if (i < 16384) { src = W2r; off = i - 12288; }
    else if (i < 24576) { src = pW1; off = i - 16384; }
    else                { src = pW2; off = i - 24576; }
    const float4* p = (const float4*)src + 2 * off;
    float4 a = p[0], c = p[1];
    u16x8 o;
    o[0]=f2b(a.x); o[1]=f2b(a.y); o[2]=f2b(a.z); o[3]=f2b(a.w);
    o[4]=f2b(c.x); o[5]=f2b(c.y); o[6]=f2b(c.z); o[7]=f2b(c.w);
    *((u16x8*)wdst + i) = o;
}

// ---------------- CSR build ----------------
__global__ void k_hist(const int* __restrict__ key, int* __restrict__ cnt, int n) {
    int e = blockIdx.x * blockDim.x + threadIdx.x;
    if (e < n) atomicAdd(&cnt[key[e]], 1);
}

__global__ void k_scan1(const int* __restrict__ cnt, int* __restrict__ part) {
    int t = threadIdx.x, lane = t & 63, w = t >> 6;
    int i = blockIdx.x * 256 + t;
    int v = (i < NN) ? cnt[i] : 0;
#pragma unroll
    for (int d = 1; d < 64; d <<= 1) v += __shfl_xor(v, d, 64);
    __shared__ int ws[4];
    if (lane == 0) ws[w] = v;
    __syncthreads();
    if (t == 0) part[blockIdx.x] = ws[0] + ws[1] + ws[2] + ws[3];
}

__global__ void k_scan2(int* __restrict__ part) {   // in-place -> exclusive bases
    int t = threadIdx.x, lane = t & 63, w = t >> 6;
    int v = (t < 196) ? part[t] : 0;
    int s = v;
#pragma unroll
    for (int d = 1; d < 64; d <<= 1) { int u = __shfl_up(s, d, 64); if (lane >= d) s += u; }
    __shared__ int ws[4];
    if (lane == 63) ws[w] = s;
    __syncthreads();
    if (t == 0) { int a = 0; for (int k = 0; k < 4; ++k) { int tmp = ws[k]; ws[k] = a; a += tmp; } }
    __syncthreads();
    if (t < 196) part[t] = ws[w] + s - v;
}

__global__ void k_scan3(const int* __restrict__ cnt, const int* __restrict__ part,
                        int* __restrict__ rowptr) {
    int t = threadIdx.x, lane = t & 63, w = t >> 6;
    int i = blockIdx.x * 256 + t;
    int v = (i < NN) ? cnt[i] : 0;
    int s = v;
#pragma unroll
    for (int d = 1; d < 64; d <<= 1) { int u = __shfl_up(s, d, 64); if (lane >= d) s += u; }
    __shared__ int ws[4];
    if (lane == 63) ws[w] = s;
    __syncthreads();
    if (t == 0) { int a = 0; for (int k = 0; k < 4; ++k) { int tmp = ws[k]; ws[k] = a; a += tmp; } }
    __syncthreads();
    if (i <= NN) rowptr[i] = part[blockIdx.x] + ws[w] + s - v;
}

__global__ void k_fill(const int* __restrict__ src, const int* __restrict__ dst,
                       const int* __restrict__ rowptr, int* __restrict__ cursor,
                       int* __restrict__ col) {
    int e = blockIdx.x * blockDim.x + threadIdx.x;
    if (e >= NE) return;
    int d = dst[e];
    int slot = atomicAdd(&cursor[d], 1);
    col[rowptr[d] + slot] = src[e];
}

// per-lane CSR gather-mean of one 128-ch row (lane owns 2 channels = 4 B), 8-deep pipelined.
// Returns packed bf16 pair — bit-identical to the old k_mean.
__device__ inline unsigned int mean_row(const unsigned short* __restrict__ feat,
                                        const int* __restrict__ rowptr,
                                        const int* __restrict__ col,
                                        int node, int lane) {
    float a0 = 0.f, a1 = 0.f;
    int beg = rowptr[node], end = rowptr[node + 1];
    int j = beg;
    for (; j + 8 <= end; j += 8) {
        int s[8];
#pragma unroll
        for (int k = 0; k < 8; ++k) s[k] = col[j + k];
        unsigned int v[8];
#pragma unroll
        for (int k = 0; k < 8; ++k)
            v[k] = *(const unsigned int*)(feat + (size_t)s[k] * 128 + lane * 2);
#pragma unroll
        for (int k = 0; k < 8; ++k) { a0 += b2f(v[k] & 0xffff); a1 += b2f(v[k] >> 16); }
    }
    if (j + 4 <= end) {
        int s[4];
#pragma unroll
        for (int k = 0; k < 4; ++k) s[k] = col[j + k];
        unsigned int v[4];
#pragma unroll
        for (int k = 0; k < 4; ++k)
            v[k] = *(const unsigned int*)(feat + (size_t)s[k] * 128 + lane * 2);
#pragma unroll
        for (int k = 0; k < 4; ++k) { a0 += b2f(v[k] & 0xffff); a1 += b2f(v[k] >> 16); }
        j += 4;
    }
    for (; j < end; ++j) {
        int s = col[j];
        unsigned int v = *(const unsigned int*)(feat + (size_t)s * 128 + lane * 2);
        a0 += b2f(v & 0xffff); a1 += b2f(v >> 16);
    }
    float inv = 1.f / fmaxf((float)(end - beg), 1.f);
    return (unsigned int)f2b(a0 * inv) | ((unsigned int)f2b(a1 * inv) << 16);
}

// ---------------- fused mean#1 + SAGE1 + layer-2 linears ----------------
// ms = mean_x (computed inline from CSR), xs = x; h = relu(bn1(...)) in LDS; Y,S out.
__global__ __launch_bounds__(256) void k_sage12(
    const unsigned short* __restrict__ xbf,
    const int* __restrict__ rowptr, const int* __restrict__ col,
    const unsigned short* __restrict__ Wl, const unsigned short* __restrict__ Wr,   // [256][128]
    const float* __restrict__ b, const float* __restrict__ bg, const float* __restrict__ bb,
    const float* __restrict__ bm, const float* __restrict__ bv,
    const unsigned short* __restrict__ W2l, const unsigned short* __restrict__ W2r, // [128][256]
    const float* __restrict__ b2,
    unsigned short* __restrict__ Y, unsigned short* __restrict__ S) {
    __shared__ unsigned short AB[64 * 256];           // 32 KB: ms|xs, then reused as hs
    unsigned short* ms = AB;
    unsigned short* xs = AB + 64 * 128;
    int t = threadIdx.x;
    int n0 = blockIdx.x * 64;
    // stage self x rows (issue first so they overlap the mean gathers)
    for (int j = 0; j < 4; ++j) {
        int idx = t + j * 256;
        int row = idx >> 4, c16 = idx & 15;
        int node = n0 + row;
        u16x8 v2 = {0,0,0,0,0,0,0,0};
        if (node < NN) v2 = *(const u16x8*)(xbf + (size_t)node * 128 + c16 * 8);
        int byte = row * 256 + ((c16 * 16) ^ ((row & 7) << 4));
        *(u16x8*)((char*)xs + byte) = v2;
    }
    // inline gather-mean: wave w owns rows w*16..w*16+15
    int w = t >> 6, lane = t & 63;
    for (int i = 0; i < 16; ++i) {
        int row = w * 16 + i;
        int node = n0 + row;
        unsigned int mv = 0;
        if (node < NN) mv = mean_row(xbf, rowptr, col, node, lane);
        int byte = row * 256 + ((lane * 4) ^ ((row & 7) << 4));
        *(unsigned int*)((char*)ms + byte) = mv;
    }
    __syncthreads();
    int l = t & 63, lr = l & 15, lh = l >> 4;
    // ---- SAGE1 GEMM ----
    f32x4 acc[4][4];
#pragma unroll
    for (int mi = 0; mi < 4; ++mi)
#pragma unroll
        for (int ni = 0; ni < 4; ++ni) { acc[mi][ni][0]=0; acc[mi][ni][1]=0; acc[mi][ni][2]=0; acc[mi][ni][3]=0; }
#pragma unroll
    for (int half = 0; half < 2; ++half) {
        const unsigned short* A = half ? xs : ms;
        const unsigned short* W = half ? Wr : Wl;
#pragma unroll
        for (int ks = 0; ks < 4; ++ks) {
            int k0 = ks * 32;
            bf16x8 a[4], wf[4];
#pragma unroll
            for (int mi = 0; mi < 4; ++mi) {
                int row = mi * 16 + lr;
                int byte = row * 256 + ((k0 * 2 + lh * 16) ^ ((row & 7) << 4));
                a[mi] = *(const bf16x8*)((const char*)A + byte);
            }
#pragma unroll
            for (int ni = 0; ni < 4; ++ni) {
                int wrow = w * 64 + ni * 16 + lr;
                wf[ni] = *(const bf16x8*)(W + (size_t)wrow * 128 + k0 + lh * 8);
            }
#pragma unroll
            for (int mi = 0; mi < 4; ++mi)
#pragma unroll
                for (int ni = 0; ni < 4; ++ni)
                    acc[mi][ni] = __builtin_amdgcn_mfma_f32_16x16x32_bf16(a[mi], wf[ni], acc[mi][ni], 0, 0, 0);
        }
    }
    __syncthreads();   // ms/xs reads done; reuse AB as hs [64][256] (512B rows, swizzled)
#pragma unroll
    for (int ni = 0; ni < 4; ++ni) {
        int ch = w * 64 + ni * 16 + lr;
        float sc = bg[ch] * rsqrtf(bv[ch] + FEPS);
        float sh = bb[ch] - bm[ch] * sc;
        float bias = b[ch];
#pragma unroll
        for (int mi = 0; mi < 4; ++mi)
#pragma unroll
            for (int r = 0; r < 4; ++r) {
                int row = mi * 16 + lh * 4 + r;
                float vv = fmaxf((acc[mi][ni][r] + bias) * sc + sh, 0.f);
                int byte = row * 512 + ((ch * 2) ^ ((row & 7) << 4));
                *(unsigned short*)((char*)AB + byte) = f2b(vv);
            }
    }
    __syncthreads();
    f32x4 aY[4][2], aS[4][2];
#pragma unroll
    for (int mi = 0; mi < 4; ++mi)
#pragma unroll
        for (int ni = 0; ni < 2; ++ni) {
            aY[mi][ni][0]=0; aY[mi][ni][1]=0; aY[mi][ni][2]=0; aY[mi][ni][3]=0;
            aS[mi][ni][0]=0; aS[mi][ni][1]=0; aS[mi][ni][2]=0; aS[mi][ni][3]=0;
        }
#pragma unroll
    for (int ks = 0; ks < 8; ++ks) {
        int k0 = ks * 32;
        bf16x8 a[4], wl[2], wr[2];
#pragma unroll
        for (int mi = 0; mi < 4; ++mi) {
            int row = mi * 16 + lr;
            int byte = row * 512 + ((k0 * 2 + lh * 16) ^ ((row & 7) << 4));
            a[mi] = *(const bf16x8*)((const char*)AB + byte);
        }
#pragma unroll
        for (int ni = 0; ni < 2; ++ni) {
            int wrow = w * 32 + ni * 16 + lr;
            wl[ni] = *(const bf16x8*)(W2l + (size_t)wrow * 256 + k0 + lh * 8);
            wr[ni] = *(const bf16x8*)(W2r + (size_t)wrow * 256 + k0 + lh * 8);
        }
#pragma unroll
        for (int mi = 0; mi < 4; ++mi)
#pragma unroll
            for (int ni = 0; ni < 2; ++ni) {
                aY[mi][ni] = __builtin_amdgcn_mfma_f32_16x16x32_bf16(a[mi], wl[ni], aY[mi][ni], 0, 0, 0);
                aS[mi][ni] = __builtin_amdgcn_mfma_f32_16x16x32_bf16(a[mi], wr[ni], aS[mi][ni], 0, 0, 0);
            }
    }
#pragma unroll
    for (int ni = 0; ni < 2; ++ni) {
        int ch = w * 32 + ni * 16 + lr;
        float bias = b2[ch];
#pragma unroll
        for (int mi = 0; mi < 4; ++mi)
#pragma unroll
            for (int r = 0; r < 4; ++r) {
                int node = n0 + mi * 16 + lh * 4 + r;
                if (node < NN) {
                    Y[(size_t)node * 128 + ch] = f2b(aY[mi][ni][r]);
                    S[(size_t)node * 128 + ch] = f2b(aS[mi][ni][r] + bias);
                }
            }
    }
}

// ---------------- fused mean#2 + decoder precompute (both sides in one block) ----------------
// z = S + mean(Y-neighbors) inline; Pa=(z@W1a^T)*sc1+c1 ; Pb=(z@W1b^T)*sc1
__global__ __launch_bounds__(256) void k_prep(
    const unsigned short* __restrict__ Ybf,    // [NN][128]
    const unsigned short* __restrict__ S,      // [NN][128]
    const int* __restrict__ rowptr, const int* __restrict__ col,
    const unsigned short* __restrict__ W1,     // [256][256] bf16
    const float* __restrict__ b1, const float* __restrict__ g1,
    const float* __restrict__ be1, const float* __restrict__ m1, const float* __restrict__ v1,
    unsigned short* __restrict__ Pa, unsigned short* __restrict__ Pb) {
    __shared__ unsigned short zs[64 * 128];
    int t = threadIdx.x;
    int n0 = blockIdx.x * 64;
    int w = t >> 6, lane = t & 63;
    // inline gather-mean of Y + add S -> zs (bit-identical to old mY round-trip path)
    for (int i = 0; i < 16; ++i) {
        int row = w * 16 + i;
        int node = n0 + row;
        unsigned int zv = 0;
        if (node < NN) {
            unsigned int mv = mean_row(Ybf, rowptr, col, node, lane);
            unsigned int sv = *(const unsigned int*)(S + (size_t)node * 128 + lane * 2);
            unsigned int lo = f2b(b2f(sv & 0xffff) + b2f(mv & 0xffff));
            unsigned int hi = f2b(b2f(sv >> 16)    + b2f(mv >> 16));
            zv = lo | (hi << 16);
        }
        int byte = row * 256 + ((lane * 4) ^ ((row & 7) << 4));
        *(unsigned int*)((char*)zs + byte) = zv;
    }
    __syncthreads();
    int l = t & 63, lr = l & 15, lh = l >> 4;
#pragma unroll
    for (int side = 0; side < 2; ++side) {
        f32x4 acc[4][4];
#pragma unroll
        for (int mi = 0; mi < 4; ++mi)
#pragma unroll
            for (int ni = 0; ni < 4; ++ni) { acc[mi][ni][0]=0; acc[mi][ni][1]=0; acc[mi][ni][2]=0; acc[mi][ni][3]=0; }
#pragma unroll
        for (int ks = 0; ks < 4; ++ks) {
            int k0 = ks * 32;
            bf16x8 a[4], wf[4];
#pragma unroll
            for (int mi = 0; mi < 4; ++mi) {
                int row = mi * 16 + lr;
                int byte = row * 256 + ((k0 * 2 + lh * 16) ^ ((row & 7) << 4));
                a[mi] = *(const bf16x8*)((const char*)zs + byte);
            }
#pragma unroll
            for (int ni = 0; ni < 4; ++ni) {
                int ch = w * 64 + ni * 16 + lr;
                wf[ni] = *(const bf16x8*)(W1 + (size_t)ch * 256 + side * 128 + k0 + lh * 8);
            }
#pragma unroll
            for (int mi = 0; mi < 4; ++mi)
#pragma unroll
                for (int ni = 0; ni < 4; ++ni)
                    acc[mi][ni] = __builtin_amdgcn_mfma_f32_16x16x32_bf16(a[mi], wf[ni], acc[mi][ni], 0, 0, 0);
        }
        unsigned short* P = side ? Pb : Pa;
#pragma unroll
        for (int ni = 0; ni < 4; ++ni) {
            int ch = w * 64 + ni * 16 + lr;
            float sc = g1[ch] * rsqrtf(v1[ch] + FEPS);
            float add = side ? 0.f : ((b1[ch] - m1[ch]) * sc + be1[ch]);
#pragma unroll
            for (int mi = 0; mi < 4; ++mi)
#pragma unroll
                for (int r = 0; r < 4; ++r) {
                    int node = n0 + mi * 16 + lh * 4 + r;
                    if (node < NN)
                        P[(size_t)node * 256 + ch] = f2b(acc[mi][ni][r] * sc + add);
                }
        }
    }
}

// ---------------- fused decoder (r5 structure): q1=relu(Pa[u]+Pb[v]); L2 GEMM; L3 dot ----------------
// 64 edges/block, gathers batch-issued (4 row-pairs in flight per lane)
__global__ __launch_bounds__(256, 5) void k_mlp(
    const unsigned short* __restrict__ Pa, const unsigned short* __restrict__ Pb,
    const int* __restrict__ pu, const int* __restrict__ pv,
    const unsigned short* __restrict__ W2, const float* __restrict__ b2,
    const float* __restrict__ g2, const float* __restrict__ be2,
    const float* __restrict__ m2, const float* __restrict__ v2,
    const float* __restrict__ W3, const float* __restrict__ b3,
    float* __restrict__ out) {
    __shared__ unsigned short q1[64 * 256];   // 32 KB, reused for q2 after MFMA drain
    int t = threadIdx.x;
    int e0 = blockIdx.x * 64;
#pragma unroll
    for (int batch = 0; batch < 2; ++batch) {
        u16x8 A[4], B[4];
        int bofs[4];
#pragma unroll
        for (int j = 0; j < 4; ++j) {
            int idx = t + (batch * 4 + j) * 256;
            int edge = idx >> 5, c16 = idx & 31;
            int ge = e0 + edge;
            if (ge < NPE) {
                int u = pu[ge], vv = pv[ge];
                A[j] = *(const u16x8*)(Pa + (size_t)u  * 256 + c16 * 8);
                B[j] = *(const u16x8*)(Pb + (size_t)vv * 256 + c16 * 8);
            } else {
                A[j] = (u16x8){0,0,0,0,0,0,0,0};
                B[j] = (u16x8){0,0,0,0,0,0,0,0};
            }
            bofs[j] = edge * 512 + ((c16 * 16) ^ ((edge & 7) << 4));
        }
#pragma unroll
        for (int j = 0; j < 4; ++j) {
            u16x8 o;
#pragma unroll
            for (int jj = 0; jj < 8; ++jj)
                o[jj] = f2b(fmaxf(b2f((unsigned short)A[j][jj]) + b2f((unsigned short)B[j][jj]), 0.f));
            *(u16x8*)((char*)q1 + bofs[j]) = o;
        }
    }
    __syncthreads();
    int w = t >> 6, l = t & 63, lr = l & 15, lh = l >> 4;
    f32x4 acc[4][2];
#pragma unroll
    for (int mi = 0; mi < 4; ++mi)
#pragma unroll
        for (int ni = 0; ni < 2; ++ni) { acc[mi][ni][0]=0; acc[mi][ni][1]=0; acc[mi][ni][2]=0; acc[mi][ni][3]=0; }
#pragma unroll
    for (int ks = 0; ks < 8; ++ks) {
        int k0 = ks * 32;
        bf16x8 a[4], wf[2];
#pragma unroll
        for (int mi = 0; mi < 4; ++mi) {
            int row = mi * 16 + lr;
            int byte = row * 512 + ((k0 * 2 + lh * 16) ^ ((row & 7) << 4));
            a[mi] = *(const bf16x8*)((const char*)q1 + byte);
        }
#pragma unroll
        for (int ni = 0; ni < 2; ++ni) {
            int wrow = w * 32 + ni * 16 + lr;
            wf[ni] = *(const bf16x8*)(W2 + (size_t)wrow * 256 + k0 + lh * 8);
        }
#pragma unroll
        for (int mi = 0; mi < 4; ++mi)
#pragma unroll
            for (int ni = 0; ni < 2; ++ni)
                acc[mi][ni] = __builtin_amdgcn_mfma_f32_16x16x32_bf16(a[mi], wf[ni], acc[mi][ni], 0, 0, 0);
    }
    __syncthreads();   // all q1 reads done; safe to overwrite with q2
#pragma unroll
    for (int ni = 0; ni < 2; ++ni) {
        int ch = w * 32 + ni * 16 + lr;
        float sc = g2[ch] * rsqrtf(v2[ch] + FEPS);
        float sh = be2[ch] - m2[ch] * sc;
        float bias = b2[ch];
#pragma unroll
        for (int mi = 0; mi < 4; ++mi)
#pragma unroll
            for (int r = 0; r < 4; ++r) {
                int row = mi * 16 + lh * 4 + r;
                float vv = fmaxf((acc[mi][ni][r] + bias) * sc + sh, 0.f);
                int byte = row * 256 + ((ch * 2) ^ ((row & 7) << 4));
                *(unsigned short*)((char*)q1 + byte) = f2b(vv);
            }
    }
    __syncthreads();
    {   // layer 3: [64x128] @ W3(128); 4 threads per edge
        int edge = t >> 2, part = t & 3;
        float p = 0.f;
#pragma unroll
        for (int s = 0; s < 4; ++s) {
            int byte = edge * 256 + ((part * 64 + s * 16) ^ ((edge & 7) << 4));
            u16x8 v = *(const u16x8*)((const char*)q1 + byte);
#pragma unroll
            for (int jj = 0; jj < 8; ++jj)
                p += b2f((unsigned short)v[jj]) * W3[part * 32 + s * 8 + jj];
        }
        p += __shfl_xor(p, 1, 64);
        p += __shfl_xor(p, 2, 64);
        int ge = e0 + edge;
        if (part == 0 && ge < NPE) out[ge] = p + b3[0];
    }
}

extern "C" void kernel_launch(void* const* d_in, const int* in_sizes, int n_in,
                              void* d_out, int out_size, void* d_ws, size_t ws_size,
                              hipStream_t stream) {
    const float* x    = (const float*)d_in[0];
    const int*   ei   = (const int*)d_in[1];
    const int*   pei  = (const int*)d_in[2];
    const float* W1l  = (const float*)d_in[3];
    const float* W1r  = (const float*)d_in[4];
    const float* b1   = (const float*)d_in[5];
    const float* bn1g = (const float*)d_in[6];
    const float* bn1b = (const float*)d_in[7];
    const float* bn1m = (const float*)d_in[8];
    const float* bn1v = (const float*)d_in[9];
    const float* W2l  = (const float*)d_in[10];
    const float* W2r  = (const float*)d_in[11];
    const float* b2   = (const float*)d_in[12];
    const float* pW1  = (const float*)d_in[13];
    const float* pb1  = (const float*)d_in[14];
    const float* pg1  = (const float*)d_in[15];
    const float* pbb1 = (const float*)d_in[16];
    const float* pm1  = (const float*)d_in[17];
    const float* pv1  = (const float*)d_in[18];
    const float* pW2  = (const float*)d_in[19];
    const float* pb2  = (const float*)d_in[20];
    const float* pg2  = (const float*)d_in[21];
    const float* pbb2 = (const float*)d_in[22];
    const float* pm2  = (const float*)d_in[23];
    const float* pv2  = (const float*)d_in[24];
    const float* pW3  = (const float*)d_in[25];
    const float* pb3  = (const float*)d_in[26];
    float* out = (float*)d_out;

    const int* src = ei;
    const int* dst = ei + NE;
    const int* pu  = pei;
    const int* pv  = pei + NPE;

    char* p = (char*)d_ws;
    auto alloc = [&](size_t bytes) -> char* {
        char* r = p; p += (bytes + 255) & ~(size_t)255; return r;
    };
    int* cnt     = (int*)alloc((size_t)NN * 4);          // zeroed by k_init (with cursor)
    int* cursor  = (int*)alloc((size_t)NN * 4);
    int* part    = (int*)alloc(256 * 4);
    int* rowptr  = (int*)alloc((size_t)(NN + 1) * 4);
    int* col     = (int*)alloc((size_t)NE * 4);
    unsigned short* xbf  = (unsigned short*)alloc((size_t)NN * 128 * 2);  // -> Pb lower half
    unsigned short* mx   = (unsigned short*)alloc((size_t)NN * 128 * 2);  // -> Pb upper half (unused otherwise)
    unsigned short* Ybf  = (unsigned short*)alloc((size_t)NN * 128 * 2);
    unsigned short* Sbf  = (unsigned short*)alloc((size_t)NN * 128 * 2);
    unsigned short* Pa   = (unsigned short*)alloc((size_t)NN * 256 * 2);
    unsigned short* W1lb = (unsigned short*)alloc((size_t)256 * 128 * 2); // contiguous weight block
    unsigned short* W1rb = (unsigned short*)alloc((size_t)256 * 128 * 2);
    unsigned short* W2lb = (unsigned short*)alloc((size_t)128 * 256 * 2);
    unsigned short* W2rb = (unsigned short*)alloc((size_t)128 * 256 * 2);
    unsigned short* pW1b = (unsigned short*)alloc((size_t)256 * 256 * 2);
    unsigned short* pW2b = (unsigned short*)alloc((size_t)128 * 256 * 2);
    unsigned short* Pb = xbf;   // [NN][256] spanning xbf+mx (dead after k_sage12)
    (void)mx;

    // 1. fused zero (cnt,cursor) + bf16 conversions
    k_init<<<3335, 256, 0, stream>>>((int4*)cnt, x, xbf,
                                     W1l, W1r, W2l, W2r, pW1, pW2, W1lb);
    // CSR build (aggregation, keyed by dst)
    k_hist<<<2500, 256, 0, stream>>>(dst, cnt, NE);
    k_scan1<<<196, 256, 0, stream>>>(cnt, part);
    k_scan2<<<1, 256, 0, stream>>>(part);
    k_scan3<<<196, 256, 0, stream>>>(cnt, part, rowptr);
    k_fill<<<2500, 256, 0, stream>>>(src, dst, rowptr, cursor, col);

    // encoder: mean#1 fused into sage12
    k_sage12<<<782, 256, 0, stream>>>(xbf, rowptr, col, W1lb, W1rb,
                                      b1, bn1g, bn1b, bn1m, bn1v,
                                      W2lb, W2rb, b2, Ybf, Sbf);
    // decoder precompute: mean#2 fused, both sides (Pb overwrites xbf+mx — dead now)
    k_prep<<<782, 256, 0, stream>>>(Ybf, Sbf, rowptr, col, pW1b,
                                    pb1, pg1, pbb1, pm1, pv1, Pa, Pb);

    // fused decoder
    k_mlp<<<(NPE + 63) / 64, 256, 0, stream>>>(Pa, Pb, pu, pv,
                                               pW2b, pb2, pg2, pbb2, pm2, pv2,
                                               pW3, pb3, out);
}

// Round 9
// 346.769 us; speedup vs baseline: 1.4602x; 1.2602x over previous
//
#include <hip/hip_runtime.h>
#include <hip/hip_bf16.h>

#define NN   50000
#define NE   640000
#define NPE  500000
#define FEPS 1e-5f

typedef __attribute__((ext_vector_type(8))) short          bf16x8;
typedef __attribute__((ext_vector_type(8))) unsigned short u16x8;
typedef __attribute__((ext_vector_type(4))) float          f32x4;

__device__ inline float b2f(unsigned short u) {
    union { unsigned int i; float f; } c; c.i = (unsigned int)u << 16; return c.f;
}
__device__ inline unsigned short f2b(float f) {
    __hip_bfloat16 h = __float2bfloat16(f);
    return *reinterpret_cast<unsigned short*>(&h);
}

// ---------------- fused init: zero cnt/cursor + all fp32->bf16 conversions ----------------
// blocks [0,98): zero 25088 int4 ; [98,3223): x ; [3223,3335): weights (contiguous dst)
__global__ __launch_bounds__(256) void k_init(
    int4* __restrict__ zdst,
    const float* __restrict__ x, unsigned short* __restrict__ xbf,
    const float* __restrict__ W1l, const float* __restrict__ W1r,
    const float* __restrict__ W2l, const float* __restrict__ W2r,
    const float* __restrict__ pW1, const float* __restrict__ pW2,
    unsigned short* __restrict__ wdst) {
    int b = blockIdx.x, t = threadIdx.x;
    if (b < 98) {
        int i = b * 256 + t;
        if (i < 25088) zdst[i] = make_int4(0, 0, 0, 0);
        return;
    }
    const float* src;
    size_t off;
    if (b < 3223) {
        int i = (b - 98) * 256 + t;
        if (i >= 800000) return;
        const float4* p = (const float4*)x + 2 * (size_t)i;
        float4 a = p[0], c = p[1];
        u16x8 o;
        o[0]=f2b(a.x); o[1]=f2b(a.y); o[2]=f2b(a.z); o[3]=f2b(a.w);
        o[4]=f2b(c.x); o[5]=f2b(c.y); o[6]=f2b(c.z); o[7]=f2b(c.w);
        *((u16x8*)xbf + i) = o;
        return;
    }
    int i = (b - 3223) * 256 + t;   // 0..28671
    if (i >= 28672) return;
    if      (i < 4096)  { src = W1l; off = i; }
    else if (i < 8192)  { src = W1r; off = i - 4096; }
    else if (i < 12288) { src = W2l; off = i - 8192; }
    else if (i < 16384) { src = W2r; off = i - 12288; }
    else if (i < 24576) { src = pW1; off = i - 16384; }
    else                { src = pW2; off = i - 24576; }
    const float4* p = (const float4*)src + 2 * off;
    float4 a = p[0], c = p[1];
    u16x8 o;
    o[0]=f2b(a.x); o[1]=f2b(a.y); o[2]=f2b(a.z); o[3]=f2b(a.w);
    o[4]=f2b(c.x); o[5]=f2b(c.y); o[6]=f2b(c.z); o[7]=f2b(c.w);
    *((u16x8*)wdst + i) = o;
}

// ---------------- CSR build ----------------
__global__ void k_hist(const int* __restrict__ key, int* __restrict__ cnt, int n) {
    int e = blockIdx.x * blockDim.x + threadIdx.x;
    if (e < n) atomicAdd(&cnt[key[e]], 1);
}

__global__ void k_scan1(const int* __restrict__ cnt, int* __restrict__ part) {
    int t = threadIdx.x, lane = t & 63, w = t >> 6;
    int i = blockIdx.x * 256 + t;
    int v = (i < NN) ? cnt[i] : 0;
#pragma unroll
    for (int d = 1; d < 64; d <<= 1) v += __shfl_xor(v, d, 64);
    __shared__ int ws[4];
    if (lane == 0) ws[w] = v;
    __syncthreads();
    if (t == 0) part[blockIdx.x] = ws[0] + ws[1] + ws[2] + ws[3];
}

__global__ void k_scan2(int* __restrict__ part) {   // in-place -> exclusive bases
    int t = threadIdx.x, lane = t & 63, w = t >> 6;
    int v = (t < 196) ? part[t] : 0;
    int s = v;
#pragma unroll
    for (int d = 1; d < 64; d <<= 1) { int u = __shfl_up(s, d, 64); if (lane >= d) s += u; }
    __shared__ int ws[4];
    if (lane == 63) ws[w] = s;
    __syncthreads();
    if (t == 0) { int a = 0; for (int k = 0; k < 4; ++k) { int tmp = ws[k]; ws[k] = a; a += tmp; } }
    __syncthreads();
    if (t < 196) part[t] = ws[w] + s - v;
}

__global__ void k_scan3(const int* __restrict__ cnt, const int* __restrict__ part,
                        int* __restrict__ rowptr) {
    int t = threadIdx.x, lane = t & 63, w = t >> 6;
    int i = blockIdx.x * 256 + t;
    int v = (i < NN) ? cnt[i] : 0;
    int s = v;
#pragma unroll
    for (int d = 1; d < 64; d <<= 1) { int u = __shfl_up(s, d, 64); if (lane >= d) s += u; }
    __shared__ int ws[4];
    if (lane == 63) ws[w] = s;
    __syncthreads();
    if (t == 0) { int a = 0; for (int k = 0; k < 4; ++k) { int tmp = ws[k]; ws[k] = a; a += tmp; } }
    __syncthreads();
    if (i <= NN) rowptr[i] = part[blockIdx.x] + ws[w] + s - v;
}

__global__ void k_fill(const int* __restrict__ src, const int* __restrict__ dst,
                       const int* __restrict__ rowptr, int* __restrict__ cursor,
                       int* __restrict__ col) {
    int e = blockIdx.x * blockDim.x + threadIdx.x;
    if (e >= NE) return;
    int d = dst[e];
    int slot = atomicAdd(&cursor[d], 1);
    col[rowptr[d] + slot] = src[e];
}

// ---------------- gather-mean (CSR), 16B/lane: 4 neighbor-rows per load instruction ----------------
// wave = 1 node; lane-group g (16 lanes) handles neighbor j+g; lane covers 8 channels.
__global__ __launch_bounds__(256) void k_mean(const unsigned short* __restrict__ feat,
                                              const int* __restrict__ rowptr,
                                              const int* __restrict__ col,
                                              unsigned short* __restrict__ outm) {
    int node = blockIdx.x * 4 + (threadIdx.x >> 6);
    int lane = threadIdx.x & 63;
    int g = lane >> 4, li = lane & 15;
    if (node >= NN) return;
    int beg = rowptr[node], end = rowptr[node + 1];
    float acc[8];
#pragma unroll
    for (int k = 0; k < 8; ++k) acc[k] = 0.f;
    int j = beg;
    for (; j + 8 <= end; j += 8) {            // 8 neighbors in flight (2 loads/lane)
        int s0 = col[j + g], s1 = col[j + 4 + g];
        u16x8 v0 = *(const u16x8*)(feat + (size_t)s0 * 128 + li * 8);
        u16x8 v1 = *(const u16x8*)(feat + (size_t)s1 * 128 + li * 8);
#pragma unroll
        for (int k = 0; k < 8; ++k)
            acc[k] += b2f((unsigned short)v0[k]) + b2f((unsigned short)v1[k]);
    }
    for (; j < end; j += 4) {                 // predicated tail, 4 at a time
        int idx = j + g;
        bool ok = idx < end;
        int s = ok ? col[idx] : col[beg];
        u16x8 v = *(const u16x8*)(feat + (size_t)s * 128 + li * 8);
        if (ok) {
#pragma unroll
            for (int k = 0; k < 8; ++k) acc[k] += b2f((unsigned short)v[k]);
        }
    }
    // reduce across the 4 lane-groups (lane bits 4,5)
#pragma unroll
    for (int k = 0; k < 8; ++k) {
        acc[k] += __shfl_xor(acc[k], 16, 64);
        acc[k] += __shfl_xor(acc[k], 32, 64);
    }
    if (g == 0) {
        float inv = 1.f / fmaxf((float)(end - beg), 1.f);
        u16x8 o;
#pragma unroll
        for (int k = 0; k < 8; ++k) o[k] = f2b(acc[k] * inv);
        *(u16x8*)(outm + (size_t)node * 128 + li * 8) = o;
    }
}

// ---------------- fused SAGE1 + layer-2 linears (r5) ----------------
__global__ __launch_bounds__(256) void k_sage12(
    const unsigned short* __restrict__ mean, const unsigned short* __restrict__ self,
    const unsigned short* __restrict__ Wl, const unsigned short* __restrict__ Wr,   // [256][128]
    const float* __restrict__ b, const float* __restrict__ bg, const float* __restrict__ bb,
    const float* __restrict__ bm, const float* __restrict__ bv,
    const unsigned short* __restrict__ W2l, const unsigned short* __restrict__ W2r, // [128][256]
    const float* __restrict__ b2,
    unsigned short* __restrict__ Y, unsigned short* __restrict__ S) {
    __shared__ unsigned short AB[64 * 256];           // 32 KB: ms|xs, then reused as hs
    unsigned short* ms = AB;
    unsigned short* xs = AB + 64 * 128;
    int t = threadIdx.x;
    int n0 = blockIdx.x * 64;
    for (int j = 0; j < 4; ++j) {
        int idx = t + j * 256;
        int row = idx >> 4, c16 = idx & 15;
        int node = n0 + row;
        u16x8 v = {0,0,0,0,0,0,0,0}, v2 = {0,0,0,0,0,0,0,0};
        if (node < NN) {
            v  = *(const u16x8*)(mean + (size_t)node * 128 + c16 * 8);
            v2 = *(const u16x8*)(self + (size_t)node * 128 + c16 * 8);
        }
        int byte = row * 256 + ((c16 * 16) ^ ((row & 7) << 4));
        *(u16x8*)((char*)ms + byte) = v;
        *(u16x8*)((char*)xs + byte) = v2;
    }
    __syncthreads();
    int w = t >> 6, l = t & 63, lr = l & 15, lh = l >> 4;
    f32x4 acc[4][4];
#pragma unroll
    for (int mi = 0; mi < 4; ++mi)
#pragma unroll
        for (int ni = 0; ni < 4; ++ni) { acc[mi][ni][0]=0; acc[mi][ni][1]=0; acc[mi][ni][2]=0; acc[mi][ni][3]=0; }
#pragma unroll
    for (int half = 0; half < 2; ++half) {
        const unsigned short* A = half ? xs : ms;
        const unsigned short* W = half ? Wr : Wl;
#pragma unroll
        for (int ks = 0; ks < 4; ++ks) {
            int k0 = ks * 32;
            bf16x8 a[4], wf[4];
#pragma unroll
            for (int mi = 0; mi < 4; ++mi) {
                int row = mi * 16 + lr;
                int byte = row * 256 + ((k0 * 2 + lh * 16) ^ ((row & 7) << 4));
                a[mi] = *(const bf16x8*)((const char*)A + byte);
            }
#pragma unroll
            for (int ni = 0; ni < 4; ++ni) {
                int wrow = w * 64 + ni * 16 + lr;
                wf[ni] = *(const bf16x8*)(W + (size_t)wrow * 128 + k0 + lh * 8);
            }
#pragma unroll
            for (int mi = 0; mi < 4; ++mi)
#pragma unroll
                for (int ni = 0; ni < 4; ++ni)
                    acc[mi][ni] = __builtin_amdgcn_mfma_f32_16x16x32_bf16(a[mi], wf[ni], acc[mi][ni], 0, 0, 0);
        }
    }
    __syncthreads();   // ms/xs reads done; reuse AB as hs [64][256] (512B rows, swizzled)
#pragma unroll
    for (int ni = 0; ni < 4; ++ni) {
        int ch = w * 64 + ni * 16 + lr;
        float sc = bg[ch] * rsqrtf(bv[ch] + FEPS);
        float sh = bb[ch] - bm[ch] * sc;
        float bias = b[ch];
#pragma unroll
        for (int mi = 0; mi < 4; ++mi)
#pragma unroll
            for (int r = 0; r < 4; ++r) {
                int row = mi * 16 + lh * 4 + r;
                float vv = fmaxf((acc[mi][ni][r] + bias) * sc + sh, 0.f);
                int byte = row * 512 + ((ch * 2) ^ ((row & 7) << 4));
                *(unsigned short*)((char*)AB + byte) = f2b(vv);
            }
    }
    __syncthreads();
    f32x4 aY[4][2], aS[4][2];
#pragma unroll
    for (int mi = 0; mi < 4; ++mi)
#pragma unroll
        for (int ni = 0; ni < 2; ++ni) {
            aY[mi][ni][0]=0; aY[mi][ni][1]=0; aY[mi][ni][2]=0; aY[mi][ni][3]=0;
            aS[mi][ni][0]=0; aS[mi][ni][1]=0; aS[mi][ni][2]=0; aS[mi][ni][3]=0;
        }
#pragma unroll
    for (int ks = 0; ks < 8; ++ks) {
        int k0 = ks * 32;
        bf16x8 a[4], wl[2], wr[2];
#pragma unroll
        for (int mi = 0; mi < 4; ++mi) {
            int row = mi * 16 + lr;
            int byte = row * 512 + ((k0 * 2 + lh * 16) ^ ((row & 7) << 4));
            a[mi] = *(const bf16x8*)((const char*)AB + byte);
        }
#pragma unroll
        for (int ni = 0; ni < 2; ++ni) {
            int wrow = w * 32 + ni * 16 + lr;
            wl[ni] = *(const bf16x8*)(W2l + (size_t)wrow * 256 + k0 + lh * 8);
            wr[ni] = *(const bf16x8*)(W2r + (size_t)wrow * 256 + k0 + lh * 8);
        }
#pragma unroll
        for (int mi = 0; mi < 4; ++mi)
#pragma unroll
            for (int ni = 0; ni < 2; ++ni) {
                aY[mi][ni] = __builtin_amdgcn_mfma_f32_16x16x32_bf16(a[mi], wl[ni], aY[mi][ni], 0, 0, 0);
                aS[mi][ni] = __builtin_amdgcn_mfma_f32_16x16x32_bf16(a[mi], wr[ni], aS[mi][ni], 0, 0, 0);
            }
    }
#pragma unroll
    for (int ni = 0; ni < 2; ++ni) {
        int ch = w * 32 + ni * 16 + lr;
        float bias = b2[ch];
#pragma unroll
        for (int mi = 0; mi < 4; ++mi)
#pragma unroll
            for (int r = 0; r < 4; ++r) {
                int node = n0 + mi * 16 + lh * 4 + r;
                if (node < NN) {
                    Y[(size_t)node * 128 + ch] = f2b(aY[mi][ni][r]);
                    S[(size_t)node * 128 + ch] = f2b(aS[mi][ni][r] + bias);
                }
            }
    }
}

// ---------------- decoder precompute: z=S+mY staged ONCE; both W1-halves per block ----------------
__global__ __launch_bounds__(256) void k_prep(
    const unsigned short* __restrict__ S,      // [NN][128]
    const unsigned short* __restrict__ mY,     // [NN][128]
    const unsigned short* __restrict__ W1,     // [256][256] bf16
    const float* __restrict__ b1, const float* __restrict__ g1,
    const float* __restrict__ be1, const float* __restrict__ m1, const float* __restrict__ v1,
    unsigned short* __restrict__ Pa, unsigned short* __restrict__ Pb) {
    __shared__ unsigned short zs[64 * 128];
    int t = threadIdx.x;
    int n0 = blockIdx.x * 64;
    for (int j = 0; j < 4; ++j) {
        int idx = t + j * 256;
        int row = idx >> 4, c16 = idx & 15;
        int node = n0 + row;
        u16x8 o = {0,0,0,0,0,0,0,0};
        if (node < NN) {
            u16x8 sv = *(const u16x8*)(S  + (size_t)node * 128 + c16 * 8);
            u16x8 mv = *(const u16x8*)(mY + (size_t)node * 128 + c16 * 8);
#pragma unroll
            for (int jj = 0; jj < 8; ++jj)
                o[jj] = f2b(b2f((unsigned short)sv[jj]) + b2f((unsigned short)mv[jj]));
        }
        int byte = row * 256 + ((c16 * 16) ^ ((row & 7) << 4));
        *(u16x8*)((char*)zs + byte) = o;
    }
    __syncthreads();
    int w = t >> 6, l = t & 63, lr = l & 15, lh = l >> 4;
#pragma unroll
    for (int side = 0; side < 2; ++side) {
        f32x4 acc[4][4];
#pragma unroll
        for (int mi = 0; mi < 4; ++mi)
#pragma unroll
            for (int ni = 0; ni < 4; ++ni) { acc[mi][ni][0]=0; acc[mi][ni][1]=0; acc[mi][ni][2]=0; acc[mi][ni][3]=0; }
#pragma unroll
        for (int ks = 0; ks < 4; ++ks) {
            int k0 = ks * 32;
            bf16x8 a[4], wf[4];
#pragma unroll
            for (int mi = 0; mi < 4; ++mi) {
                int row = mi * 16 + lr;
                int byte = row * 256 + ((k0 * 2 + lh * 16) ^ ((row & 7) << 4));
                a[mi] = *(const bf16x8*)((const char*)zs + byte);
            }
#pragma unroll
            for (int ni = 0; ni < 4; ++ni) {
                int ch = w * 64 + ni * 16 + lr;
                wf[ni] = *(const bf16x8*)(W1 + (size_t)ch * 256 + side * 128 + k0 + lh * 8);
            }
#pragma unroll
            for (int mi = 0; mi < 4; ++mi)
#pragma unroll
                for (int ni = 0; ni < 4; ++ni)
                    acc[mi][ni] = __builtin_amdgcn_mfma_f32_16x16x32_bf16(a[mi], wf[ni], acc[mi][ni], 0, 0, 0);
        }
        unsigned short* P = side ? Pb : Pa;
#pragma unroll
        for (int ni = 0; ni < 4; ++ni) {
            int ch = w * 64 + ni * 16 + lr;
            float sc = g1[ch] * rsqrtf(v1[ch] + FEPS);
            float add = side ? 0.f : ((b1[ch] - m1[ch]) * sc + be1[ch]);
#pragma unroll
            for (int mi = 0; mi < 4; ++mi)
#pragma unroll
                for (int r = 0; r < 4; ++r) {
                    int node = n0 + mi * 16 + lh * 4 + r;
                    if (node < NN)
                        P[(size_t)node * 256 + ch] = f2b(acc[mi][ni][r] * sc + add);
                }
        }
    }
}

// ---------------- fused decoder (r5): q1=relu(Pa[u]+Pb[v]); L2 GEMM; L3 dot. 64 edges/block ----------------
__global__ __launch_bounds__(256, 5) void k_mlp(
    const unsigned short* __restrict__ Pa, const unsigned short* __restrict__ Pb,
    const int* __restrict__ pu, const int* __restrict__ pv,
    const unsigned short* __restrict__ W2, const float* __restrict__ b2,
    const float* __restrict__ g2, const float* __restrict__ be2,
    const float* __restrict__ m2, const float* __restrict__ v2,
    const float* __restrict__ W3, const float* __restrict__ b3,
    float* __restrict__ out) {
    __shared__ unsigned short q1[64 * 256];   // 32 KB, reused for q2 after MFMA drain
    int t = threadIdx.x;
    int e0 = blockIdx.x * 64;
#pragma unroll
    for (int batch = 0; batch < 2; ++batch) {
        u16x8 A[4], B[4];
        int bofs[4];
#pragma unroll
        for (int j = 0; j < 4; ++j) {
            int idx = t + (batch * 4 + j) * 256;
            int edge = idx >> 5, c16 = idx & 31;
            int ge = e0 + edge;
            if (ge < NPE) {
                int u = pu[ge], vv = pv[ge];
                A[j] = *(const u16x8*)(Pa + (size_t)u  * 256 + c16 * 8);
                B[j] = *(const u16x8*)(Pb + (size_t)vv * 256 + c16 * 8);
            } else {
                A[j] = (u16x8){0,0,0,0,0,0,0,0};
                B[j] = (u16x8){0,0,0,0,0,0,0,0};
            }
            bofs[j] = edge * 512 + ((c16 * 16) ^ ((edge & 7) << 4));
        }
#pragma unroll
        for (int j = 0; j < 4; ++j) {
            u16x8 o;
#pragma unroll
            for (int jj = 0; jj < 8; ++jj)
                o[jj] = f2b(fmaxf(b2f((unsigned short)A[j][jj]) + b2f((unsigned short)B[j][jj]), 0.f));
            *(u16x8*)((char*)q1 + bofs[j]) = o;
        }
    }
    __syncthreads();
    int w = t >> 6, l = t & 63, lr = l & 15, lh = l >> 4;
    f32x4 acc[4][2];
#pragma unroll
    for (int mi = 0; mi < 4; ++mi)
#pragma unroll
        for (int ni = 0; ni < 2; ++ni) { acc[mi][ni][0]=0; acc[mi][ni][1]=0; acc[mi][ni][2]=0; acc[mi][ni][3]=0; }
#pragma unroll
    for (int ks = 0; ks < 8; ++ks) {
        int k0 = ks * 32;
        bf16x8 a[4], wf[2];
#pragma unroll
        for (int mi = 0; mi < 4; ++mi) {
            int row = mi * 16 + lr;
            int byte = row * 512 + ((k0 * 2 + lh * 16) ^ ((row & 7) << 4));
            a[mi] = *(const bf16x8*)((const char*)q1 + byte);
        }
#pragma unroll
        for (int ni = 0; ni < 2; ++ni) {
            int wrow = w * 32 + ni * 16 + lr;
            wf[ni] = *(const bf16x8*)(W2 + (size_t)wrow * 256 + k0 + lh * 8);
        }
#pragma unroll
        for (int mi = 0; mi < 4; ++mi)
#pragma unroll
            for (int ni = 0; ni < 2; ++ni)
                acc[mi][ni] = __builtin_amdgcn_mfma_f32_16x16x32_bf16(a[mi], wf[ni], acc[mi][ni], 0, 0, 0);
    }
    __syncthreads();   // all q1 reads done; safe to overwrite with q2
#pragma unroll
    for (int ni = 0; ni < 2; ++ni) {
        int ch = w * 32 + ni * 16 + lr;
        float sc = g2[ch] * rsqrtf(v2[ch] + FEPS);
        float sh = be2[ch] - m2[ch] * sc;
        float bias = b2[ch];
#pragma unroll
        for (int mi = 0; mi < 4; ++mi)
#pragma unroll
            for (int r = 0; r < 4; ++r) {
                int row = mi * 16 + lh * 4 + r;
                float vv = fmaxf((acc[mi][ni][r] + bias) * sc + sh, 0.f);
                int byte = row * 256 + ((ch * 2) ^ ((row & 7) << 4));
                *(unsigned short*)((char*)q1 + byte) = f2b(vv);
            }
    }
    __syncthreads();
    {   // layer 3: [64x128] @ W3(128); 4 threads per edge
        int edge = t >> 2, part = t & 3;
        float p = 0.f;
#pragma unroll
        for (int s = 0; s < 4; ++s) {
            int byte = edge * 256 + ((part * 64 + s * 16) ^ ((edge & 7) << 4));
            u16x8 v = *(const u16x8*)((const char*)q1 + byte);
#pragma unroll
            for (int jj = 0; jj < 8; ++jj)
                p += b2f((unsigned short)v[jj]) * W3[part * 32 + s * 8 + jj];
        }
        p += __shfl_xor(p, 1, 64);
        p += __shfl_xor(p, 2, 64);
        int ge = e0 + edge;
        if (part == 0 && ge < NPE) out[ge] = p + b3[0];
    }
}

extern "C" void kernel_launch(void* const* d_in, const int* in_sizes, int n_in,
                              void* d_out, int out_size, void* d_ws, size_t ws_size,
                              hipStream_t stream) {
    const float* x    = (const float*)d_in[0];
    const int*   ei   = (const int*)d_in[1];
    const int*   pei  = (const int*)d_in[2];
    const float* W1l  = (const float*)d_in[3];
    const float* W1r  = (const float*)d_in[4];
    const float* b1   = (const float*)d_in[5];
    const float* bn1g = (const float*)d_in[6];
    const float* bn1b = (const float*)d_in[7];
    const float* bn1m = (const float*)d_in[8];
    const float* bn1v = (const float*)d_in[9];
    const float* W2l  = (const float*)d_in[10];
    const float* W2r  = (const float*)d_in[11];
    const float* b2   = (const float*)d_in[12];
    const float* pW1  = (const float*)d_in[13];
    const float* pb1  = (const float*)d_in[14];
    const float* pg1  = (const float*)d_in[15];
    const float* pbb1 = (const float*)d_in[16];
    const float* pm1  = (const float*)d_in[17];
    const float* pv1  = (const float*)d_in[18];
    const float* pW2  = (const float*)d_in[19];
    const float* pb2  = (const float*)d_in[20];
    const float* pg2  = (const float*)d_in[21];
    const float* pbb2 = (const float*)d_in[22];
    const float* pm2  = (const float*)d_in[23];
    const float* pv2  = (const float*)d_in[24];
    const float* pW3  = (const float*)d_in[25];
    const float* pb3  = (const float*)d_in[26];
    float* out = (float*)d_out;

    const int* src = ei;
    const int* dst = ei + NE;
    const int* pu  = pei;
    const int* pv  = pei + NPE;

    char* p = (char*)d_ws;
    auto alloc = [&](size_t bytes) -> char* {
        char* r = p; p += (bytes + 255) & ~(size_t)255; return r;
    };
    int* cnt     = (int*)alloc((size_t)NN * 4);          // zeroed by k_init (with cursor)
    int* cursor  = (int*)alloc((size_t)NN * 4);
    int* part    = (int*)alloc(256 * 4);
    int* rowptr  = (int*)alloc((size_t)(NN + 1) * 4);
    int* col     = (int*)alloc((size_t)NE * 4);
    unsigned short* xbf  = (unsigned short*)alloc((size_t)NN * 128 * 2);  // -> Pb lower half
    unsigned short* mx   = (unsigned short*)alloc((size_t)NN * 128 * 2);  // -> Pb upper half
    unsigned short* Ybf  = (unsigned short*)alloc((size_t)NN * 128 * 2);
    unsigned short* mY   = (unsigned short*)alloc((size_t)NN * 128 * 2);
    unsigned short* Sbf  = (unsigned short*)alloc((size_t)NN * 128 * 2);
    unsigned short* Pa   = (unsigned short*)alloc((size_t)NN * 256 * 2);
    unsigned short* W1lb = (unsigned short*)alloc((size_t)256 * 128 * 2); // contiguous weight block
    unsigned short* W1rb = (unsigned short*)alloc((size_t)256 * 128 * 2);
    unsigned short* W2lb = (unsigned short*)alloc((size_t)128 * 256 * 2);
    unsigned short* W2rb = (unsigned short*)alloc((size_t)128 * 256 * 2);
    unsigned short* pW1b = (unsigned short*)alloc((size_t)256 * 256 * 2);
    unsigned short* pW2b = (unsigned short*)alloc((size_t)128 * 256 * 2);
    unsigned short* Pb = xbf;   // [NN][256] spanning xbf+mx (dead after k_sage12)

    // 1. fused zero (cnt,cursor) + bf16 conversions
    k_init<<<3335, 256, 0, stream>>>((int4*)cnt, x, xbf,
                                     W1l, W1r, W2l, W2r, pW1, pW2, W1lb);
    // CSR build (aggregation, keyed by dst)
    k_hist<<<2500, 256, 0, stream>>>(dst, cnt, NE);
    k_scan1<<<196, 256, 0, stream>>>(cnt, part);
    k_scan2<<<1, 256, 0, stream>>>(part);
    k_scan3<<<196, 256, 0, stream>>>(cnt, part, rowptr);
    k_fill<<<2500, 256, 0, stream>>>(src, dst, rowptr, cursor, col);

    // encoder
    k_mean<<<12500, 256, 0, stream>>>(xbf, rowptr, col, mx);
    k_sage12<<<782, 256, 0, stream>>>(mx, xbf, W1lb, W1rb, b1, bn1g, bn1b, bn1m, bn1v,
                                      W2lb, W2rb, b2, Ybf, Sbf);
    k_mean<<<12500, 256, 0, stream>>>(Ybf, rowptr, col, mY);

    // decoder precompute (Pb overwrites xbf+mx — dead now)
    k_prep<<<782, 256, 0, stream>>>(Sbf, mY, pW1b, pb1, pg1, pbb1, pm1, pv1, Pa, Pb);

    // fused decoder
    k_mlp<<<(NPE + 63) / 64, 256, 0, stream>>>(Pa, Pb, pu, pv,
                                               pW2b, pb2, pg2, pbb2, pm2, pv2,
                                               pW3, pb3, out);
}